// Round 5
// baseline (103.183 us; speedup 1.0000x reference)
//
#include <hip/hip_runtime.h>

#define EMBD 768
#define HS 64
#define S_LEN 4096
#define QB 32
#define BK 64

typedef __attribute__((ext_vector_type(8))) short short8;
typedef __attribute__((ext_vector_type(4))) short short4_t;
typedef __attribute__((ext_vector_type(4))) float f32x4;
typedef unsigned short ushort_t;
typedef unsigned int uint_t;

static __device__ __forceinline__ ushort_t f2bf(float f) {
    union { float f; unsigned u; } x; x.f = f;
    unsigned r = x.u + 0x7fffu + ((x.u >> 16) & 1u);   // RNE
    return (ushort_t)(r >> 16);
}

static __device__ __forceinline__ uint_t cvt_pk_bf16(float lo, float hi) {
    uint_t r;
    asm volatile("v_cvt_pk_bf16_f32 %0, %1, %2" : "=v"(r) : "v"(lo), "v"(hi));
    return r;
}

static __device__ __forceinline__ short8 pack_bf8(float4 a, float4 b) {
    union { short8 s; uint_t u[4]; } r;
    r.u[0] = cvt_pk_bf16(a.x, a.y); r.u[1] = cvt_pk_bf16(a.z, a.w);
    r.u[2] = cvt_pk_bf16(b.x, b.y); r.u[3] = cvt_pk_bf16(b.z, b.w);
    return r.s;
}

// ---------------- W prep: Wt[192][768] bf16, Wt[c][k] = W_sel[k][c%64] ----------------
__global__ __launch_bounds__(256) void wprep_kernel(
    const float* __restrict__ Wq, const float* __restrict__ Wk, const float* __restrict__ Wv,
    ushort_t* __restrict__ Wt)
{
    __shared__ float ws[64][65];
    const int blk  = blockIdx.x;           // 36 = 3 W x 12 k-blocks
    const int widx = blk / 12, kblk = blk % 12;
    const float* W = (widx == 0) ? Wq : (widx == 1) ? Wk : Wv;
    const int k0 = kblk * 64;
    const int t  = threadIdx.x;
    const int r  = t >> 2, c0 = (t & 3) * 16;
#pragma unroll
    for (int i = 0; i < 4; ++i) {
        float4 v = *(const float4*)(W + (size_t)(k0 + r) * HS + c0 + i * 4);
        ws[c0 + i*4 + 0][r] = v.x; ws[c0 + i*4 + 1][r] = v.y;
        ws[c0 + i*4 + 2][r] = v.z; ws[c0 + i*4 + 3][r] = v.w;
    }
    __syncthreads();
    const int c = t >> 2, kc = (t & 3) * 16;
    ushort_t* dst = Wt + (size_t)(widx * 64 + c) * EMBD + k0 + kc;
#pragma unroll
    for (int i = 0; i < 4; ++i) {
        short4_t p = {(short)f2bf(ws[c][kc + i*4 + 0]), (short)f2bf(ws[c][kc + i*4 + 1]),
                      (short)f2bf(ws[c][kc + i*4 + 2]), (short)f2bf(ws[c][kc + i*4 + 3])};
        *(short4_t*)(dst + i * 4) = p;
    }
}

// ---------------- QKV via MFMA: no LDS staging, no barriers, reg pipeline ----------------
// 512 thr: 8 waves = 2 row-groups x 4 col-groups. A-frags converted in-register from
// global x; B-frags from Wt. Q output pre-scaled by 1/8.
__global__ __launch_bounds__(512) void qkv_kernel(
    const float* __restrict__ x, const ushort_t* __restrict__ Wt,
    ushort_t* __restrict__ Qg, ushort_t* __restrict__ Kg, ushort_t* __restrict__ Vtg)
{
    __shared__ float Vs[32][65];
    const int t    = threadIdx.x;
    const int w    = t >> 6;
    const int lane = t & 63;
    const int l15  = lane & 15;
    const int l4   = lane >> 4;
    const int mg   = w >> 2;
    const int cg   = w & 3;
    const int row0 = blockIdx.x * 32;

    const float* xr = x + (size_t)(row0 + mg * 16 + l15) * EMBD + l4 * 8;
    const ushort_t* wp0 = Wt + (size_t)(cg * 16 + l15) * EMBD + l4 * 8;
    const ushort_t* wp1 = wp0 + (size_t)64 * EMBD;
    const ushort_t* wp2 = wp0 + (size_t)128 * EMBD;

    f32x4 acc0 = (f32x4){0.f,0.f,0.f,0.f}, acc1 = acc0, acc2 = acc0;

    float4 xa[2][2][2];     // [buf][ks][half] — buf index is compile-time after unroll
    short8 wb[2][3][2];

    // prologue: kt = 0
#pragma unroll
    for (int ks = 0; ks < 2; ++ks) {
        xa[0][ks][0] = *(const float4*)(xr + ks * 32);
        xa[0][ks][1] = *(const float4*)(xr + ks * 32 + 4);
        wb[0][0][ks] = *(const short8*)(wp0 + ks * 32);
        wb[0][1][ks] = *(const short8*)(wp1 + ks * 32);
        wb[0][2][ks] = *(const short8*)(wp2 + ks * 32);
    }

#pragma unroll
    for (int kt = 0; kt < 12; ++kt) {
        const int cur = kt & 1, nxt = cur ^ 1;
        if (kt < 11) {
            const int o = (kt + 1) * 64;
#pragma unroll
            for (int ks = 0; ks < 2; ++ks) {
                xa[nxt][ks][0] = *(const float4*)(xr + o + ks * 32);
                xa[nxt][ks][1] = *(const float4*)(xr + o + ks * 32 + 4);
                wb[nxt][0][ks] = *(const short8*)(wp0 + o + ks * 32);
                wb[nxt][1][ks] = *(const short8*)(wp1 + o + ks * 32);
                wb[nxt][2][ks] = *(const short8*)(wp2 + o + ks * 32);
            }
        }
#pragma unroll
        for (int ks = 0; ks < 2; ++ks) {
            short8 af = pack_bf8(xa[cur][ks][0], xa[cur][ks][1]);
            acc0 = __builtin_amdgcn_mfma_f32_16x16x32_bf16(af, wb[cur][0][ks], acc0, 0, 0, 0);
            acc1 = __builtin_amdgcn_mfma_f32_16x16x32_bf16(af, wb[cur][1][ks], acc1, 0, 0, 0);
            acc2 = __builtin_amdgcn_mfma_f32_16x16x32_bf16(af, wb[cur][2][ks], acc2, 0, 0, 0);
        }
    }

    // epilogue: Q (pre-scaled 1/8) / K direct, V via LDS transpose
    const size_t grow0 = (size_t)row0 + mg * 16 + l4 * 4;
    const int col = cg * 16 + l15;
#pragma unroll
    for (int r = 0; r < 4; ++r) {
        Qg[(grow0 + r) * HS + col] = f2bf(acc0[r] * 0.125f);
        Kg[(grow0 + r) * HS + col] = f2bf(acc1[r]);
        Vs[mg * 16 + l4 * 4 + r][col] = acc2[r];
    }
    __syncthreads();
    const int vcol = t >> 3, vr0 = (t & 7) * 4;
    const int bb = row0 >> 12, s0 = row0 & 4095;
    short4_t vp = {(short)f2bf(Vs[vr0][vcol]),     (short)f2bf(Vs[vr0 + 1][vcol]),
                   (short)f2bf(Vs[vr0 + 2][vcol]), (short)f2bf(Vs[vr0 + 3][vcol])};
    *(short4_t*)(Vtg + ((size_t)bb * HS + vcol) * S_LEN + s0 + vr0) = vp;
}

// ---------------- MFMA flash attention: prefetched K-frags, pure defer-max ----------------
__global__ __launch_bounds__(256) void attn_kernel(
    const ushort_t* __restrict__ Qg, const ushort_t* __restrict__ Kg,
    const ushort_t* __restrict__ Vtg, float* __restrict__ out, int B)
{
    __shared__ char smem[34304];
    const int t    = threadIdx.x;
    const int w    = t >> 6;
    const int lane = t & 63;
    const int l15  = lane & 15;
    const int l4   = lane >> 4;

    // XCD swizzle: batch b -> XCDs {2b,2b+1}; biggest q-tiles first within each batch
    const int g = blockIdx.x;
    int b, qt;
    if (B == 4) { b = (g & 7) >> 1; qt = (S_LEN/QB - 1) - ((g >> 3) * 2 + (g & 1)); }
    else        { b = g % B;        qt = (S_LEN/QB - 1) - (g / B); }
    const int q0 = qt * QB;
    const int ntiles = (q0 + QB + BK - 1) >> 6;

    char* myP = smem + w * 4096;     // [32 q][64 k] bf16, byte ^= ((q&7)<<4)
    const int psw = (l15 & 7) << 4;

    const ushort_t* Qbase = Qg + ((size_t)b * S_LEN + q0) * HS;
    short8 qf[2][2];
#pragma unroll
    for (int sub = 0; sub < 2; ++sub)
#pragma unroll
        for (int c = 0; c < 2; ++c)
            qf[sub][c] = *(const short8*)(Qbase + (sub * 16 + l15) * HS + c * 32 + l4 * 8);

    f32x4 acc[2][4];
#pragma unroll
    for (int i = 0; i < 2; ++i)
#pragma unroll
        for (int j = 0; j < 4; ++j) acc[i][j] = (f32x4){0.f,0.f,0.f,0.f};
    float m[2] = {-3e38f, -3e38f};
    float lsum[2] = {0.f, 0.f};

    const ushort_t* Kb_ = Kg  + (size_t)b * S_LEN * HS;
    const ushort_t* Vb_ = Vtg + (size_t)b * HS * S_LEN;

    auto process = [&](short8 (&CURB)[4][2], short8 (&NXTB)[4][2], int kb) {
        const int k0 = kb * BK;
        short8 vf[4][2];
#pragma unroll
        for (int ds = 0; ds < 4; ++ds)
#pragma unroll
            for (int ks = 0; ks < 2; ++ks)
                vf[ds][ks] = *(const short8*)(Vb_ + (size_t)(ds * 16 + l15) * S_LEN + k0 + ks * 32 + l4 * 8);
        if (kb + 4 < ntiles) {
            const int kn = (kb + 4) * BK;
#pragma unroll
            for (int st = 0; st < 4; ++st)
#pragma unroll
                for (int c = 0; c < 2; ++c)
                    NXTB[st][c] = *(const short8*)(Kb_ + (size_t)(kn + st * 16 + l15) * HS + c * 32 + l4 * 8);
        }
        const bool lastTile = (kb == ntiles - 1);
#pragma unroll
        for (int sub = 0; sub < 2; ++sub) {
            f32x4 sT[4];
#pragma unroll
            for (int st = 0; st < 4; ++st) {
                f32x4 z = (f32x4){0.f,0.f,0.f,0.f};
                z = __builtin_amdgcn_mfma_f32_16x16x32_bf16(CURB[st][0], qf[sub][0], z, 0, 0, 0);
                z = __builtin_amdgcn_mfma_f32_16x16x32_bf16(CURB[st][1], qf[sub][1], z, 0, 0, 0);
                sT[st] = z;
            }
            const int q = q0 + sub * 16 + l15;
            if (lastTile) {
#pragma unroll
                for (int st = 0; st < 4; ++st)
#pragma unroll
                    for (int r = 0; r < 4; ++r)
                        if (k0 + st * 16 + l4 * 4 + r > q) sT[st][r] = -3e38f;
            }
            // in-lane max tree (no shfl in steady state)
            float a0 = fmaxf(fmaxf(sT[0][0], sT[0][1]), fmaxf(sT[0][2], sT[0][3]));
            float a1 = fmaxf(fmaxf(sT[1][0], sT[1][1]), fmaxf(sT[1][2], sT[1][3]));
            float a2 = fmaxf(fmaxf(sT[2][0], sT[2][1]), fmaxf(sT[2][2], sT[2][3]));
            float a3 = fmaxf(fmaxf(sT[3][0], sT[3][1]), fmaxf(sT[3][2], sT[3][3]));
            float mt = fmaxf(fmaxf(a0, a1), fmaxf(a2, a3));
            if (__any(mt > m[sub] + 8.f)) {           // rare: full max + rescale
                mt = fmaxf(mt, __shfl_xor(mt, 16));
                mt = fmaxf(mt, __shfl_xor(mt, 32));
                float mn = fmaxf(m[sub], mt);
                float corr = __expf(m[sub] - mn);
                lsum[sub] *= corr;
#pragma unroll
                for (int ds = 0; ds < 4; ++ds)
#pragma unroll
                    for (int r = 0; r < 4; ++r) acc[sub][ds][r] *= corr;
                m[sub] = mn;
            }
            char* pr = myP + (sub * 16 + l15) * 128;
            float la = 0.f;
#pragma unroll
            for (int st = 0; st < 4; ++st) {
                float p0 = __expf(sT[st][0] - m[sub]);
                float p1 = __expf(sT[st][1] - m[sub]);
                float p2 = __expf(sT[st][2] - m[sub]);
                float p3 = __expf(sT[st][3] - m[sub]);
                la += (p0 + p1) + (p2 + p3);
                uint2 pk; pk.x = cvt_pk_bf16(p0, p1); pk.y = cvt_pk_bf16(p2, p3);
                *(uint2*)(pr + ((st * 32 + l4 * 8) ^ psw)) = pk;
            }
            lsum[sub] += la;
            short8 pb0 = *(const short8*)(pr + ((l4 * 16) ^ psw));
            short8 pb1 = *(const short8*)(pr + ((64 + l4 * 16) ^ psw));
#pragma unroll
            for (int ds = 0; ds < 4; ++ds) {
                acc[sub][ds] = __builtin_amdgcn_mfma_f32_16x16x32_bf16(vf[ds][0], pb0, acc[sub][ds], 0, 0, 0);
                acc[sub][ds] = __builtin_amdgcn_mfma_f32_16x16x32_bf16(vf[ds][1], pb1, acc[sub][ds], 0, 0, 0);
            }
        }
    };

    short8 kfA[4][2], kfB[4][2];
    int kb = w;
    if (kb < ntiles) {
        const int k0 = kb * BK;
#pragma unroll
        for (int st = 0; st < 4; ++st)
#pragma unroll
            for (int c = 0; c < 2; ++c)
                kfA[st][c] = *(const short8*)(Kb_ + (size_t)(k0 + st * 16 + l15) * HS + c * 32 + l4 * 8);
    }
    while (kb < ntiles) {
        process(kfA, kfB, kb); kb += 4;
        if (kb >= ntiles) break;
        process(kfB, kfA, kb); kb += 4;
    }

#pragma unroll
    for (int sub = 0; sub < 2; ++sub) {
        lsum[sub] += __shfl_xor(lsum[sub], 16);
        lsum[sub] += __shfl_xor(lsum[sub], 32);
    }

    // in-block combine of 4 key-split partials
    __syncthreads();
    float* accb = (float*)smem;                       // [4][32][65]
    float* mb   = (float*)(smem + 4 * 32 * 65 * 4);   // [4][32]
    float* lb   = mb + 128;
#pragma unroll
    for (int sub = 0; sub < 2; ++sub) {
#pragma unroll
        for (int ds = 0; ds < 4; ++ds)
#pragma unroll
            for (int r = 0; r < 4; ++r)
                accb[(w * 32 + sub * 16 + l15) * 65 + ds * 16 + l4 * 4 + r] = acc[sub][ds][r];
        if (l4 == 0) {
            mb[w * 32 + sub * 16 + l15] = m[sub];
            lb[w * 32 + sub * 16 + l15] = lsum[sub];
        }
    }
    __syncthreads();

    const int d = t & 63;
#pragma unroll
    for (int pass = 0; pass < 8; ++pass) {
        const int row = (t >> 6) + pass * 4;          // 0..31
        float m0 = mb[row], m1 = mb[32 + row], m2 = mb[64 + row], m3 = mb[96 + row];
        float ms = fmaxf(fmaxf(m0, m1), fmaxf(m2, m3));
        float e0 = __expf(m0 - ms), e1 = __expf(m1 - ms), e2 = __expf(m2 - ms), e3 = __expf(m3 - ms);
        float o  = accb[(0 * 32 + row) * 65 + d] * e0 + accb[(1 * 32 + row) * 65 + d] * e1
                 + accb[(2 * 32 + row) * 65 + d] * e2 + accb[(3 * 32 + row) * 65 + d] * e3;
        float ll = lb[row] * e0 + lb[32 + row] * e1 + lb[64 + row] * e2 + lb[96 + row] * e3;
        out[((size_t)b * S_LEN + q0 + row) * HS + d] = o / ll;
    }
}

extern "C" void kernel_launch(void* const* d_in, const int* in_sizes, int n_in,
                              void* d_out, int out_size, void* d_ws, size_t ws_size,
                              hipStream_t stream) {
    const float* x  = (const float*)d_in[0];
    const float* Wq = (const float*)d_in[1];
    const float* Wk = (const float*)d_in[2];
    const float* Wv = (const float*)d_in[3];
    float* out = (float*)d_out;

    const int rows = in_sizes[0] / EMBD;   // B*S
    const int B    = rows / S_LEN;

    ushort_t* Qb = (ushort_t*)d_ws;
    ushort_t* Kb = Qb + (size_t)rows * HS;
    ushort_t* Vt = Kb + (size_t)rows * HS;
    ushort_t* Wt = Vt + (size_t)rows * HS;

    hipLaunchKernelGGL(wprep_kernel, dim3(36), dim3(256), 0, stream, Wq, Wk, Wv, Wt);
    hipLaunchKernelGGL(qkv_kernel, dim3(rows / 32), dim3(512), 0, stream,
                       x, Wt, Qb, Kb, Vt);
    hipLaunchKernelGGL(attn_kernel, dim3(B * (S_LEN / QB)), dim3(256), 0, stream,
                       Qb, Kb, Vt, out, B);
}